// Round 8
// baseline (3003.608 us; speedup 1.0000x reference)
//
#include <hip/hip_runtime.h>
#include <hip/hip_bf16.h>

#define D_MODEL 1024
#define RANK 64
#define NCOMP 16
#define NKNOW 16384
#define TOPK 8
#define NTOK 8192   // B*S
#define MAXG 48     // candidate-group cap per token (groups of 8 j's)
#define NS 6        // rescore slots per lane (MAXG*8/64)

typedef __attribute__((ext_vector_type(4))) float f32x4;
typedef __attribute__((ext_vector_type(8))) short s16x8;

static __device__ __forceinline__ unsigned short f2bf(float f) {
  union { float f; unsigned u; } v; v.f = f;
  unsigned r = v.u + 0x7FFFu + ((v.u >> 16) & 1u);
  return (unsigned short)(r >> 16);
}
static __device__ __forceinline__ float bf2f(unsigned short h) {
  union { unsigned u; float f; } v; v.u = ((unsigned)h) << 16;
  return v.f;
}

// ---------------------------------------------------------------------------
// K1: T_part[ks] = X(8192 x kl) @ B(kl x 1024), B[d][c] = cn[c>>6][d][c&63].
// 256x128 tile, 256 threads, 16x8 micro-tile (0.75 B/FMA LDS intensity),
// K-step 16, double-buffered LDS -> ONE barrier per K-step.
// A-tile LDS: logical row r -> phys col (r>>3)*12 + (r&7) (48B chunk pitch:
// b128-aligned, reads are 4 disjoint bank-quads x 16-lane broadcast = free).
// B-tile: proven R5 layout (12-float chunk pitch, 2-way free).
// ---------------------------------------------------------------------------
__global__ __launch_bounds__(256, 2) void k1_gemm(const float* __restrict__ X,
                                                  const float* __restrict__ CN,
                                                  float* __restrict__ T,
                                                  int kl) {
  __shared__ float As[2][16][384];   // 48KB
  __shared__ float Bs[2][16][192];   // 24KB
  const int bid = blockIdx.x & 255;
  const int ks = blockIdx.x >> 8;       // K-part
  const int bx = bid & 7;               // col block 0..7
  const int by = bid >> 3;              // row block 0..31
  const int tid = threadIdx.x;
  const int tx = tid & 15, ty = tid >> 4;
  const int row0 = by * 256, col0 = bx * 128;
  const int kbeg = ks * kl;
  const int nk = kl >> 4;
  T += (size_t)ks * (8192 * 1024);

  // A staging: thread owns row (row0+tid), 16 k's per step
  const float* Aptr = X + (size_t)(row0 + tid) * 1024 + kbeg;
  const int apc = (tid >> 3) * 12 + (tid & 7);
  // B staging: k-row bd, col chunk bc..bc+7 (never straddles an n boundary)
  const int bd = tid >> 4;
  const int bc = tx * 8;
  const float* Bptr = CN + (size_t)((col0 + bc) >> 6) * (1024 * 64) + bd * 64
                         + ((col0 + bc) & 63) + (size_t)kbeg * 64;
  const int bpc = tx * 12;

  f32x4 acc[16][2] = {};

  // prologue: load tile 0, store to buf 0, prefetch tile 1 regs
  f32x4 a0 = *(const f32x4*)(Aptr);
  f32x4 a1 = *(const f32x4*)(Aptr + 4);
  f32x4 a2 = *(const f32x4*)(Aptr + 8);
  f32x4 a3 = *(const f32x4*)(Aptr + 12);
  f32x4 b0 = *(const f32x4*)(Bptr);
  f32x4 b1 = *(const f32x4*)(Bptr + 4);
#pragma unroll
  for (int e = 0; e < 4; e++) {
    As[0][e][apc]      = a0[e];
    As[0][4 + e][apc]  = a1[e];
    As[0][8 + e][apc]  = a2[e];
    As[0][12 + e][apc] = a3[e];
  }
  *(f32x4*)&Bs[0][bd][bpc] = b0;
  *(f32x4*)&Bs[0][bd][bpc + 4] = b1;
  if (nk > 1) {
    a0 = *(const f32x4*)(Aptr + 16);
    a1 = *(const f32x4*)(Aptr + 20);
    a2 = *(const f32x4*)(Aptr + 24);
    a3 = *(const f32x4*)(Aptr + 28);
    b0 = *(const f32x4*)(Bptr + 1024);
    b1 = *(const f32x4*)(Bptr + 1028);
  }
  __syncthreads();

  for (int kk = 0; kk < nk; ++kk) {
    const int cur = kk & 1;
#pragma unroll
    for (int d = 0; d < 16; d++) {
      const f32x4 av0 = *(const f32x4*)&As[cur][d][ty * 24];
      const f32x4 av1 = *(const f32x4*)&As[cur][d][ty * 24 + 4];
      const f32x4 av2 = *(const f32x4*)&As[cur][d][ty * 24 + 12];
      const f32x4 av3 = *(const f32x4*)&As[cur][d][ty * 24 + 16];
      const f32x4 bv0 = *(const f32x4*)&Bs[cur][d][tx * 12];
      const f32x4 bv1 = *(const f32x4*)&Bs[cur][d][tx * 12 + 4];
#pragma unroll
      for (int i = 0; i < 4; i++) {
#pragma unroll
        for (int j = 0; j < 4; j++) {
          acc[i][0][j]      = fmaf(av0[i], bv0[j], acc[i][0][j]);
          acc[i][1][j]      = fmaf(av0[i], bv1[j], acc[i][1][j]);
          acc[4 + i][0][j]  = fmaf(av1[i], bv0[j], acc[4 + i][0][j]);
          acc[4 + i][1][j]  = fmaf(av1[i], bv1[j], acc[4 + i][1][j]);
          acc[8 + i][0][j]  = fmaf(av2[i], bv0[j], acc[8 + i][0][j]);
          acc[8 + i][1][j]  = fmaf(av2[i], bv1[j], acc[8 + i][1][j]);
          acc[12 + i][0][j] = fmaf(av3[i], bv0[j], acc[12 + i][0][j]);
          acc[12 + i][1][j] = fmaf(av3[i], bv1[j], acc[12 + i][1][j]);
        }
      }
    }
    if (kk + 1 < nk) {
      const int nxt = cur ^ 1;
#pragma unroll
      for (int e = 0; e < 4; e++) {
        As[nxt][e][apc]      = a0[e];
        As[nxt][4 + e][apc]  = a1[e];
        As[nxt][8 + e][apc]  = a2[e];
        As[nxt][12 + e][apc] = a3[e];
      }
      *(f32x4*)&Bs[nxt][bd][bpc] = b0;
      *(f32x4*)&Bs[nxt][bd][bpc + 4] = b1;
      if (kk + 2 < nk) {
        const int ko = (kk + 2) * 16;
        a0 = *(const f32x4*)(Aptr + ko);
        a1 = *(const f32x4*)(Aptr + ko + 4);
        a2 = *(const f32x4*)(Aptr + ko + 8);
        a3 = *(const f32x4*)(Aptr + ko + 12);
        b0 = *(const f32x4*)(Bptr + (size_t)ko * 64);
        b1 = *(const f32x4*)(Bptr + (size_t)ko * 64 + 4);
      }
    }
    __syncthreads();
  }
#pragma unroll
  for (int r = 0; r < 16; r++) {
    float* op = T + (size_t)(row0 + ty * 16 + r) * 1024 + col0 + tx * 8;
    *(f32x4*)op = acc[r][0];
    *(f32x4*)(op + 4) = acc[r][1];
  }
}

// ---------------------------------------------------------------------------
// K1b: Q[tok][r] = sum_n mw[tok][n] * (T0+T1)[tok][n*64+r]; emit bf16 copy.
// ---------------------------------------------------------------------------
__global__ __launch_bounds__(256) void k1b_weight(const float* __restrict__ T,
                                                  const float* __restrict__ MW,
                                                  float* __restrict__ Qf,
                                                  unsigned short* __restrict__ Qb,
                                                  int kparts) {
  const int gid = blockIdx.x * 256 + threadIdx.x;  // 0..524287
  const int tok = gid >> 6, r = gid & 63;
  float q = 0.f;
#pragma unroll
  for (int n = 0; n < 16; n++) {
    float tv = T[(size_t)tok * 1024 + n * 64 + r];
    if (kparts == 2)
      tv += T[(size_t)(8192 * 1024) + (size_t)tok * 1024 + n * 64 + r];
    q = fmaf(MW[tok * 16 + n], tv, q);
  }
  Qf[gid] = q;
  Qb[gid] = f2bf(q);
}

// ---------------------------------------------------------------------------
// K1c: Kb = bf16(knowledge_K)
// ---------------------------------------------------------------------------
__global__ __launch_bounds__(256) void k1c_cvt(const float* __restrict__ Kf,
                                               unsigned short* __restrict__ Kb) {
  const int gid = blockIdx.x * 256 + threadIdx.x;  // one per 4 elems
  f32x4 v = *(const f32x4*)(Kf + (size_t)gid * 4);
  unsigned short o0 = f2bf(v[0]), o1 = f2bf(v[1]), o2 = f2bf(v[2]), o3 = f2bf(v[3]);
  unsigned long long pack = (unsigned long long)o0 | ((unsigned long long)o1 << 16)
                          | ((unsigned long long)o2 << 32) | ((unsigned long long)o3 << 48);
  *(unsigned long long*)(Kb + (size_t)gid * 4) = pack;
}

// ---------------------------------------------------------------------------
// K2s: SINGLE screening pass. Per lane/tt: gm4 = max(c[0..3]); pair slices
// via shfl_xor(16) -> group-of-8 max; stash bf16 in LDS [tok][g] (pad 136),
// then coalesced 16B row writes to GM[tok][2048] at the end. GM layout
// (element g of token row = jsl*128 + 2*tt + (slice>>1)) matches k2b.
// ---------------------------------------------------------------------------
__global__ __launch_bounds__(256) void k2s_screen(
    const unsigned short* __restrict__ Qb,
    const unsigned short* __restrict__ Kb,
    unsigned short* __restrict__ GM) {
  __shared__ unsigned short sh[4][16][136];
  const int tid = threadIdx.x;
  const int wv = tid >> 6, lane = tid & 63;
  const int gw = blockIdx.x * 4 + wv;     // 0..8191
  const int tg = gw >> 4;                 // token group 0..511
  const int jsl = gw & 15;                // j-slice 0..15
  const int tb = tg * 16;
  const int myTok = lane & 15;
  const int slice = lane >> 4;            // 0..3

  const s16x8 bf0 = *(const s16x8*)(Qb + (size_t)(tb + myTok) * 64 + slice * 8);
  const s16x8 bf1 = *(const s16x8*)(Qb + (size_t)(tb + myTok) * 64 + 32 + slice * 8);

  const int j0 = jsl * 1024;
  const unsigned short* ap0 = Kb + (size_t)(j0 + myTok) * 64 + slice * 8;
  s16x8 af0 = *(const s16x8*)(ap0);
  s16x8 af1 = *(const s16x8*)(ap0 + 32);
  const bool writer = (slice & 1) == 0;
  const int sub = slice >> 1;

  for (int tt = 0; tt < 64; ++tt) {
    f32x4 c = {0.f, 0.f, 0.f, 0.f};
    c = __builtin_amdgcn_mfma_f32_16x16x32_bf16(af0, bf0, c, 0, 0, 0);
    c = __builtin_amdgcn_mfma_f32_16x16x32_bf16(af1, bf1, c, 0, 0, 0);
    if (tt + 1 < 64) {
      const unsigned short* ap = ap0 + (size_t)(tt + 1) * 16 * 64;
      af0 = *(const s16x8*)(ap);
      af1 = *(const s16x8*)(ap + 32);
    }
    const float gm4 = fmaxf(fmaxf(c[0], c[1]), fmaxf(c[2], c[3]));
    const float gm8 = fmaxf(gm4, __shfl_xor(gm4, 16));
    if (writer) sh[wv][myTok][2 * tt + sub] = f2bf(gm8);
  }
  __syncthreads();
  // coalesced write: lane -> token (lane>>2), 4 x 16B chunks
  {
    const int t = lane >> 2, cb = (lane & 3) * 8;
    unsigned short* orow = GM + (size_t)(tb + t) * 2048 + jsl * 128;
#pragma unroll
    for (int ch = 0; ch < 4; ch++)
      *(s16x8*)(orow + cb + ch * 32) = *(const s16x8*)&sh[wv][t][cb + ch * 32];
  }
}

// ---------------------------------------------------------------------------
// K2b: one wave per token. Read 2048 group-maxima -> thr = 8th-largest
// lane-max - margin (>=8 groups guaranteed) -> compact candidate groups ->
// exact f32 rescore of <=MAXG*8 j's -> exact top-8 (desc score, asc idx) ->
// softmax -> gather V -> outputs.
// ---------------------------------------------------------------------------
__global__ __launch_bounds__(256) void k2b_select(
    const float* __restrict__ Qf, const float* __restrict__ Kf,
    const float* __restrict__ V, const unsigned short* __restrict__ GM,
    float* __restrict__ out, float* __restrict__ out_idx,
    float* __restrict__ out_w) {
  __shared__ float qsh[4][64];
  __shared__ int csh[4][MAXG];
  __shared__ int scnt[4];
  const int tid = threadIdx.x;
  const int wv = tid >> 6, lane = tid & 63;
  const int tok = blockIdx.x * 4 + wv;    // 0..8191

  if (lane == 0) scnt[wv] = 0;
  qsh[wv][lane] = Qf[(size_t)tok * 64 + lane];

  // load 32 group-maxima per lane: groups g = i*256 + lane*4 + e
  unsigned long long gv[8];
  const unsigned long long* gmp =
      (const unsigned long long*)(GM + (size_t)tok * 2048);
#pragma unroll
  for (int i = 0; i < 8; i++) gv[i] = gmp[i * 64 + lane];

  float lm = -1e30f;
#pragma unroll
  for (int i = 0; i < 8; i++)
#pragma unroll
    for (int e = 0; e < 4; e++)
      lm = fmaxf(lm, bf2f((unsigned short)(gv[i] >> (e * 16))));

  // 8th-largest of the 64 lane-maxima (ties drop together -> thr only lower)
  float v = lm, m8 = -1e30f;
#pragma unroll
  for (int e = 0; e < 8; e++) {
    float m = v;
#pragma unroll
    for (int d = 1; d < 64; d <<= 1) m = fmaxf(m, __shfl_xor(m, d));
    m8 = m;
    if (e < 7) v = (v == m) ? -1e30f : v;
  }
  const float thr = m8 - 0.04f;

  // compact candidate groups (order irrelevant: exact rescore decides)
#pragma unroll
  for (int i = 0; i < 8; i++) {
#pragma unroll
    for (int e = 0; e < 4; e++) {
      const float g = bf2f((unsigned short)(gv[i] >> (e * 16)));
      if (g >= thr) {
        const int s = atomicAdd(&scnt[wv], 1);
        if (s < MAXG) csh[wv][s] = i * 256 + lane * 4 + e;
      }
    }
  }
  int ng = scnt[wv];
  if (ng > MAXG) ng = MAXG;
  const int nj = ng * 8;

  // exact f32 rescore
  float scR[NS]; int jR[NS];
#pragma unroll
  for (int s = 0; s < NS; s++) {
    scR[s] = -1e30f; jR[s] = 0x7fffffff;
    if (s * 64 < nj) {                    // wave-uniform
      const int ci = s * 64 + lane;
      if (ci < nj) {
        const int j = csh[wv][ci >> 3] * 8 + (ci & 7);
        const float* kp = Kf + (size_t)j * 64;
        float acc = 0.f;
#pragma unroll
        for (int k = 0; k < 64; k += 4) {
          const f32x4 qv = *(const f32x4*)&qsh[wv][k];
          const f32x4 kv = *(const f32x4*)(kp + k);
          acc = fmaf(qv[0], kv[0], acc);
          acc = fmaf(qv[1], kv[1], acc);
          acc = fmaf(qv[2], kv[2], acc);
          acc = fmaf(qv[3], kv[3], acc);
        }
        scR[s] = acc * 0.125f; jR[s] = j;
      }
    }
  }

  // exact top-8 (desc score, asc idx)
  float wsv[8]; int wjv[8];
#pragma unroll
  for (int e = 0; e < 8; e++) {
    float ms = scR[0]; int mj = jR[0];
#pragma unroll
    for (int s = 1; s < NS; s++)
      if (scR[s] > ms || (scR[s] == ms && jR[s] < mj)) { ms = scR[s]; mj = jR[s]; }
#pragma unroll
    for (int d = 1; d < 64; d <<= 1) {
      const float rs = __shfl_xor(ms, d);
      const int rj = __shfl_xor(mj, d);
      if (rs > ms || (rs == ms && rj < mj)) { ms = rs; mj = rj; }
    }
    wsv[e] = ms; wjv[e] = mj;
#pragma unroll
    for (int s = 0; s < NS; s++)
      if (jR[s] == mj) { scR[s] = -1e30f; jR[s] = 0x7fffffff; }
  }

  // softmax (redundant on all lanes)
  const float m0 = wsv[0];
  float ex[8], sum = 0.f;
#pragma unroll
  for (int r = 0; r < 8; r++) { ex[r] = expf(wsv[r] - m0); sum += ex[r]; }
  const float inv = 1.f / sum;

  if (lane == 0) {
#pragma unroll
    for (int r = 0; r < 8; r++) {
      out_idx[(size_t)tok * 8 + r] = (float)wjv[r];
      out_w[(size_t)tok * 8 + r] = ex[r] * inv;
    }
  }

  // gather V: lane owns dims [lane*16, +16)
  f32x4 a0 = {0.f,0.f,0.f,0.f}, a1 = a0, a2 = a0, a3 = a0;
#pragma unroll
  for (int r = 0; r < 8; r++) {
    const float w = ex[r] * inv;
    const float* vp = V + (size_t)wjv[r] * 1024 + lane * 16;
    const f32x4 v0 = *(const f32x4*)(vp);
    const f32x4 v1 = *(const f32x4*)(vp + 4);
    const f32x4 v2 = *(const f32x4*)(vp + 8);
    const f32x4 v3 = *(const f32x4*)(vp + 12);
    a0 += w * v0; a1 += w * v1; a2 += w * v2; a3 += w * v3;
  }
  float* op = out + (size_t)tok * 1024 + lane * 16;
  *(f32x4*)(op)      = a0;
  *(f32x4*)(op + 4)  = a1;
  *(f32x4*)(op + 8)  = a2;
  *(f32x4*)(op + 12) = a3;
}

// ---------------------------------------------------------------------------
extern "C" void kernel_launch(void* const* d_in, const int* in_sizes, int n_in,
                              void* d_out, int out_size, void* d_ws, size_t ws_size,
                              hipStream_t stream) {
  const float* x  = (const float*)d_in[0];   // [2,4096,1024]
  const float* mw = (const float*)d_in[1];   // [2,4096,16]
  const float* cn = (const float*)d_in[2];   // [16,1024,64]
  const float* kK = (const float*)d_in[3];   // [16384,64]
  const float* kV = (const float*)d_in[4];   // [16384,1024]

  float* out  = (float*)d_out;               // 8192*1024
  float* oidx = out + (size_t)NTOK * D_MODEL;       // 8192*8
  float* ow   = oidx + (size_t)NTOK * TOPK;         // 8192*8

  // KS=2 needs: T 2x32MiB | Qf 2MiB | Qb 1MiB | Kb 2MiB = 72351744 B.
  // GM (32MiB) overlays T part 0 (dead after k1b). Falls back to KS=1.
  const size_t TSZ = (size_t)8192 * 1024 * 4;
  const int KS = (ws_size >= 2 * TSZ + 2097152 + 1048576 + 2097152) ? 2 : 1;
  const size_t tailOff = (size_t)KS * TSZ;

  float* T = (float*)d_ws;
  unsigned short* GM = (unsigned short*)d_ws;
  float* Qf = (float*)((char*)d_ws + tailOff);
  unsigned short* Qb = (unsigned short*)((char*)d_ws + tailOff + 2097152);
  unsigned short* Kb = (unsigned short*)((char*)d_ws + tailOff + 3145728);

  k1_gemm<<<256 * KS, 256, 0, stream>>>(x, cn, T, 1024 / KS);
  k1b_weight<<<2048, 256, 0, stream>>>(T, mw, Qf, Qb, KS);
  k1c_cvt<<<1024, 256, 0, stream>>>(kK, Kb);
  k2s_screen<<<2048, 256, 0, stream>>>(Qb, Kb, GM);
  k2b_select<<<2048, 256, 0, stream>>>(Qf, kK, kV, GM, out, oidx, ow);

  (void)in_sizes; (void)n_in; (void)out_size; (void)ws_size;
}

// Round 12
// 339.693 us; speedup vs baseline: 8.8421x; 8.8421x over previous
//
#include <hip/hip_runtime.h>
#include <hip/hip_bf16.h>

#define D_MODEL 1024
#define RANK 64
#define NCOMP 16
#define NKNOW 16384
#define TOPK 8
#define NTOK 8192   // B*S
#define MAXG 48     // candidate-group cap per token (groups of 8 j's)
#define NS 6        // rescore slots per lane (MAXG*8/64)

typedef __attribute__((ext_vector_type(4))) float f32x4;
typedef __attribute__((ext_vector_type(8))) short s16x8;
typedef unsigned short us;

static __device__ __forceinline__ us f2bf(float f) {
  union { float f; unsigned u; } v; v.f = f;
  unsigned r = v.u + 0x7FFFu + ((v.u >> 16) & 1u);
  return (us)(r >> 16);
}
static __device__ __forceinline__ float bf2f(us h) {
  union { unsigned u; float f; } v; v.u = ((unsigned)h) << 16;
  return v.f;
}

// async global->LDS, 16B per lane; LDS dest = wave-uniform base + lane*16.
#define GLOAD16(g, l)                                                        \
  __builtin_amdgcn_global_load_lds(                                          \
      (const __attribute__((address_space(1))) void*)(g),                    \
      (__attribute__((address_space(3))) void*)(l), 16, 0, 0)

// RNE 3-way split: x = h + m + l + r, |r| <= 2^-24 |x|.
#define SPLIT3(f, h, m, l)                                                   \
  do {                                                                       \
    h = f2bf(f);                                                             \
    const float r1_ = (f) - bf2f(h);                                         \
    m = f2bf(r1_);                                                           \
    const float r2_ = r1_ - bf2f(m);                                         \
    l = f2bf(r2_);                                                           \
  } while (0)

// ---------------------------------------------------------------------------
// K1cb3: transpose + 3-way RNE-split CN -> Bh,Bm,Bl [1024 c][1024 d],
// Bt[c][d] = cn[c>>6][d][c&63]. Structure proven in R6 (k1cb).
// ---------------------------------------------------------------------------
__global__ __launch_bounds__(256) void k1cb3(const float* __restrict__ CN,
                                             us* __restrict__ Bh,
                                             us* __restrict__ Bm,
                                             us* __restrict__ Bl) {
  __shared__ float tile[64][65];
  const int n = blockIdx.x >> 4, dt = blockIdx.x & 15;
  const int tid = threadIdx.x;
  {
    const int d = tid >> 2, rc = (tid & 3) * 16;
    const float* p = CN + ((size_t)n * 1024 + dt * 64 + d) * 64 + rc;
#pragma unroll
    for (int e = 0; e < 16; e += 4) {
      const f32x4 v = *(const f32x4*)(p + e);
      tile[d][rc + e]     = v[0];
      tile[d][rc + e + 1] = v[1];
      tile[d][rc + e + 2] = v[2];
      tile[d][rc + e + 3] = v[3];
    }
  }
  __syncthreads();
  {
    const int r = tid >> 2, dc = (tid & 3) * 16;
    s16x8 oh[2], om[2], ol[2];
#pragma unroll
    for (int g = 0; g < 2; g++)
#pragma unroll
      for (int e = 0; e < 8; e++) {
        const float v = tile[dc + g * 8 + e][r];
        us h, m, l;
        SPLIT3(v, h, m, l);
        oh[g][e] = (short)h; om[g][e] = (short)m; ol[g][e] = (short)l;
      }
    const size_t base = (size_t)(n * 64 + r) * 1024 + dt * 64 + dc;
#pragma unroll
    for (int g = 0; g < 2; g++) {
      *(s16x8*)(Bh + base + g * 8) = oh[g];
      *(s16x8*)(Bm + base + g * 8) = om[g];
      *(s16x8*)(Bl + base + g * 8) = ol[g];
    }
  }
}

// ---------------------------------------------------------------------------
// K1m3: T = Xh@Bh + [Xh@Bm + Xm@Bh + Xh@Bl + Xm@Bm + Xl@Bh]  (3-way RNE).
// SPLIT ACCUMULATORS: accH takes only the hh product (1024-add stream, f32
// noise ~= the passing f32-chain's); accC takes the 5 correction products
// (magnitude ~2^-8 of accH -> negligible rounding). Merged in epilogue.
// This removes the 6x-interleaved-accumulation noise that flipped R10/R11.
// 128x128 tile, 4 waves (2x2), BK=32, grid 512. Bs double-buffered via
// global_load_lds (24 gloads/tile); As reg-staged with on-the-fly RNE split.
// ---------------------------------------------------------------------------
__global__ __launch_bounds__(256) void k1m3(const float* __restrict__ X,
                                            const us* __restrict__ Bh,
                                            const us* __restrict__ Bm,
                                            const us* __restrict__ Bl,
                                            float* __restrict__ T) {
  __shared__ us As[3][4][128][8];      // 24 KB [split][kq][row][8]
  __shared__ us Bs[2][3][4][128][8];   // 48 KB [buf][split][kq][col][8]
  const int tid = threadIdx.x;
  const int w = tid >> 6, lane = tid & 63;
  const int wr = w >> 1, wc = w & 1;
  const int l15 = lane & 15, kq = lane >> 4;
  const int by = blockIdx.x >> 3, bx = blockIdx.x & 7;
  const int row0 = by * 128, col0 = bx * 128;

  // X reg-staging: thread -> row sr, k-half sh (16 k's per step)
  const int sr = tid & 127, sh = tid >> 7;
  const float* xp = X + (size_t)(row0 + sr) * 1024 + sh * 16;

  // B gload staging: wave w handles pairs p = w*3+i (p = split*4 + kq),
  // each pair = 2 col-half gloads (cols 0..63 and 64..127).
  const us* bsrc0[3]; const us* bsrc1[3];
  int bs_s[3], bs_q[3];
#pragma unroll
  for (int i = 0; i < 3; i++) {
    const int p = w * 3 + i;
    const int s = p >> 2, q = p & 3;
    bs_s[i] = s; bs_q[i] = q;
    const us* base = (s == 0) ? Bh : (s == 1) ? Bm : Bl;
    bsrc0[i] = base + (size_t)(col0 + lane) * 1024 + q * 8;
    bsrc1[i] = base + (size_t)(col0 + 64 + lane) * 1024 + q * 8;
  }

  f32x4 accH[4][4] = {};   // hh product only
  f32x4 accC[4][4] = {};   // correction products
  f32x4 xr[4];
  s16x8 creg[6];

  // ---- prologue: B gloads for kk=0 -> buf 0; X load+convert for kk=0
#pragma unroll
  for (int i = 0; i < 3; i++) {
    GLOAD16(bsrc0[i], &Bs[0][bs_s[i]][bs_q[i]][0][0]);
    GLOAD16(bsrc1[i], &Bs[0][bs_s[i]][bs_q[i]][64][0]);
  }
#pragma unroll
  for (int g = 0; g < 4; g++) xr[g] = *(const f32x4*)(xp + g * 4);
#pragma unroll
  for (int g = 0; g < 4; g++)
#pragma unroll
    for (int e = 0; e < 4; e++) {
      us h, m, l;
      SPLIT3(xr[g][e], h, m, l);
      const int c = (g * 4 + e) >> 3, e8 = (g * 4 + e) & 7;
      creg[c][e8] = (short)h; creg[2 + c][e8] = (short)m; creg[4 + c][e8] = (short)l;
    }

  for (int kk = 0; kk < 32; ++kk) {
    const int cur = kk & 1;
    // X ds_write (As free: prev iteration's trailing barrier passed)
    *(s16x8*)&As[0][sh * 2][sr][0]     = creg[0];
    *(s16x8*)&As[0][sh * 2 + 1][sr][0] = creg[1];
    *(s16x8*)&As[1][sh * 2][sr][0]     = creg[2];
    *(s16x8*)&As[1][sh * 2 + 1][sr][0] = creg[3];
    *(s16x8*)&As[2][sh * 2][sr][0]     = creg[4];
    *(s16x8*)&As[2][sh * 2 + 1][sr][0] = creg[5];
    __syncthreads();   // drains B gloads for kk (vmcnt 0) + As writes

    if (kk + 1 < 32) {
      const int ko = (kk + 1) * 32;
#pragma unroll
      for (int i = 0; i < 3; i++) {
        GLOAD16(bsrc0[i] + ko, &Bs[cur ^ 1][bs_s[i]][bs_q[i]][0][0]);
        GLOAD16(bsrc1[i] + ko, &Bs[cur ^ 1][bs_s[i]][bs_q[i]][64][0]);
      }
#pragma unroll
      for (int g = 0; g < 4; g++) xr[g] = *(const f32x4*)(xp + ko + g * 4);
    }

    // 6 products, 96 MFMA; hh -> accH, corrections -> accC
#define PROD(sa, sb, ACC)                                                     \
    do {                                                                      \
      s16x8 af[4];                                                            \
      _Pragma("unroll")                                                       \
      for (int mm = 0; mm < 4; mm++)                                          \
        af[mm] = *(const s16x8*)&As[sa][kq][wr * 64 + mm * 16 + l15][0];      \
      _Pragma("unroll")                                                       \
      for (int nn = 0; nn < 4; nn++) {                                        \
        const s16x8 bfr =                                                     \
            *(const s16x8*)&Bs[cur][sb][kq][wc * 64 + nn * 16 + l15][0];      \
        _Pragma("unroll")                                                     \
        for (int mm = 0; mm < 4; mm++)                                        \
          ACC[mm][nn] = __builtin_amdgcn_mfma_f32_16x16x32_bf16(              \
              af[mm], bfr, ACC[mm][nn], 0, 0, 0);                             \
      }                                                                       \
    } while (0)

    PROD(0, 0, accH);
    PROD(0, 1, accC); PROD(1, 0, accC); PROD(0, 2, accC);
    PROD(2, 0, accC); PROD(1, 1, accC);
#undef PROD

    if (kk + 1 < 32) {
#pragma unroll
      for (int g = 0; g < 4; g++)
#pragma unroll
        for (int e = 0; e < 4; e++) {
          us h, m, l;
          SPLIT3(xr[g][e], h, m, l);
          const int c = (g * 4 + e) >> 3, e8 = (g * 4 + e) & 7;
          creg[c][e8] = (short)h; creg[2 + c][e8] = (short)m;
          creg[4 + c][e8] = (short)l;
        }
    }
    __syncthreads();   // all waves done reading As/Bs[cur]
  }

#pragma unroll
  for (int mm = 0; mm < 4; mm++)
#pragma unroll
    for (int nn = 0; nn < 4; nn++)
#pragma unroll
      for (int r = 0; r < 4; r++)
        T[(size_t)(row0 + wr * 64 + mm * 16 + kq * 4 + r) * 1024
          + col0 + wc * 64 + nn * 16 + l15] = accH[mm][nn][r] + accC[mm][nn][r];
}

// ---------------------------------------------------------------------------
// K1b: Q[tok][r] = sum_n mw[tok][n] * T[tok][n*64+r]; also emit bf16 copy.
// ---------------------------------------------------------------------------
__global__ __launch_bounds__(256) void k1b_weight(const float* __restrict__ T,
                                                  const float* __restrict__ MW,
                                                  float* __restrict__ Qf,
                                                  us* __restrict__ Qb) {
  const int gid = blockIdx.x * 256 + threadIdx.x;  // 0..524287
  const int tok = gid >> 6, r = gid & 63;
  float q = 0.f;
#pragma unroll
  for (int n = 0; n < 16; n++)
    q = fmaf(MW[tok * 16 + n], T[(size_t)tok * 1024 + n * 64 + r], q);
  Qf[gid] = q;
  Qb[gid] = f2bf(q);
}

// ---------------------------------------------------------------------------
// K1c: Kb = bf16(knowledge_K)
// ---------------------------------------------------------------------------
__global__ __launch_bounds__(256) void k1c_cvt(const float* __restrict__ Kf,
                                               us* __restrict__ Kb) {
  const int gid = blockIdx.x * 256 + threadIdx.x;  // one per 4 elems
  f32x4 v = *(const f32x4*)(Kf + (size_t)gid * 4);
  us o0 = f2bf(v[0]), o1 = f2bf(v[1]), o2 = f2bf(v[2]), o3 = f2bf(v[3]);
  unsigned long long pack = (unsigned long long)o0 | ((unsigned long long)o1 << 16)
                          | ((unsigned long long)o2 << 32) | ((unsigned long long)o3 << 48);
  *(unsigned long long*)(Kb + (size_t)gid * 4) = pack;
}

// ---------------------------------------------------------------------------
// K2s: SINGLE screening pass. Per lane/tt: gm4 = max(c[0..3]); pair slices
// via shfl_xor(16) -> group-of-8 max; stash bf16 in LDS [tok][g] (pad 136),
// then coalesced 16B row writes to GM[tok][2048]. Layout matches k2b.
// ---------------------------------------------------------------------------
__global__ __launch_bounds__(256) void k2s_screen(
    const us* __restrict__ Qb, const us* __restrict__ Kb,
    us* __restrict__ GM) {
  __shared__ us sh[4][16][136];
  const int tid = threadIdx.x;
  const int wv = tid >> 6, lane = tid & 63;
  const int gw = blockIdx.x * 4 + wv;     // 0..8191
  const int tg = gw >> 4;                 // token group 0..511
  const int jsl = gw & 15;                // j-slice 0..15
  const int tb = tg * 16;
  const int myTok = lane & 15;
  const int slice = lane >> 4;            // 0..3

  const s16x8 bf0 = *(const s16x8*)(Qb + (size_t)(tb + myTok) * 64 + slice * 8);
  const s16x8 bf1 = *(const s16x8*)(Qb + (size_t)(tb + myTok) * 64 + 32 + slice * 8);

  const int j0 = jsl * 1024;
  const us* ap0 = Kb + (size_t)(j0 + myTok) * 64 + slice * 8;
  s16x8 af0 = *(const s16x8*)(ap0);
  s16x8 af1 = *(const s16x8*)(ap0 + 32);
  const bool writer = (slice & 1) == 0;
  const int sub = slice >> 1;

  for (int tt = 0; tt < 64; ++tt) {
    f32x4 c = {0.f, 0.f, 0.f, 0.f};
    c = __builtin_amdgcn_mfma_f32_16x16x32_bf16(af0, bf0, c, 0, 0, 0);
    c = __builtin_amdgcn_mfma_f32_16x16x32_bf16(af1, bf1, c, 0, 0, 0);
    if (tt + 1 < 64) {
      const us* ap = ap0 + (size_t)(tt + 1) * 16 * 64;
      af0 = *(const s16x8*)(ap);
      af1 = *(const s16x8*)(ap + 32);
    }
    const float gm4 = fmaxf(fmaxf(c[0], c[1]), fmaxf(c[2], c[3]));
    const float gm8 = fmaxf(gm4, __shfl_xor(gm4, 16));
    if (writer) sh[wv][myTok][2 * tt + sub] = f2bf(gm8);
  }
  __syncthreads();
  {
    const int t = lane >> 2, cb = (lane & 3) * 8;
    us* orow = GM + (size_t)(tb + t) * 2048 + jsl * 128;
#pragma unroll
    for (int ch = 0; ch < 4; ch++)
      *(s16x8*)(orow + cb + ch * 32) = *(const s16x8*)&sh[wv][t][cb + ch * 32];
  }
}

// ---------------------------------------------------------------------------
// K2b: one wave per token. 2048 group-maxima -> thr = 8th-largest lane-max -
// margin -> compact groups -> exact f32 rescore -> exact top-8 (desc score,
// asc idx) -> softmax -> gather V -> outputs. V-gather index masked to
// [0,NKNOW) so a sentinel can never fault (no effect on correct runs).
// ---------------------------------------------------------------------------
__global__ __launch_bounds__(256) void k2b_select(
    const float* __restrict__ Qf, const float* __restrict__ Kf,
    const float* __restrict__ V, const us* __restrict__ GM,
    float* __restrict__ out, float* __restrict__ out_idx,
    float* __restrict__ out_w) {
  __shared__ float qsh[4][64];
  __shared__ int csh[4][MAXG];
  __shared__ int scnt[4];
  const int tid = threadIdx.x;
  const int wv = tid >> 6, lane = tid & 63;
  const int tok = blockIdx.x * 4 + wv;    // 0..8191

  if (lane == 0) scnt[wv] = 0;
  qsh[wv][lane] = Qf[(size_t)tok * 64 + lane];

  unsigned long long gv[8];
  const unsigned long long* gmp =
      (const unsigned long long*)(GM + (size_t)tok * 2048);
#pragma unroll
  for (int i = 0; i < 8; i++) gv[i] = gmp[i * 64 + lane];

  float lm = -1e30f;
#pragma unroll
  for (int i = 0; i < 8; i++)
#pragma unroll
    for (int e = 0; e < 4; e++)
      lm = fmaxf(lm, bf2f((us)(gv[i] >> (e * 16))));

  float v = lm, m8 = -1e30f;
#pragma unroll
  for (int e = 0; e < 8; e++) {
    float m = v;
#pragma unroll
    for (int d = 1; d < 64; d <<= 1) m = fmaxf(m, __shfl_xor(m, d));
    m8 = m;
    if (e < 7) v = (v == m) ? -1e30f : v;
  }
  const float thr = m8 - 0.04f;

#pragma unroll
  for (int i = 0; i < 8; i++) {
#pragma unroll
    for (int e = 0; e < 4; e++) {
      const float g = bf2f((us)(gv[i] >> (e * 16)));
      if (g >= thr) {
        const int s = atomicAdd(&scnt[wv], 1);
        if (s < MAXG) csh[wv][s] = i * 256 + lane * 4 + e;
      }
    }
  }
  int ng = scnt[wv];
  if (ng > MAXG) ng = MAXG;
  const int nj = ng * 8;

  float scR[NS]; int jR[NS];
#pragma unroll
  for (int s = 0; s < NS; s++) {
    scR[s] = -1e30f; jR[s] = 0x7fffffff;
    if (s * 64 < nj) {
      const int ci = s * 64 + lane;
      if (ci < nj) {
        const int j = csh[wv][ci >> 3] * 8 + (ci & 7);
        const float* kp = Kf + (size_t)j * 64;
        float acc = 0.f;
#pragma unroll
        for (int k = 0; k < 64; k += 4) {
          const f32x4 qv = *(const f32x4*)&qsh[wv][k];
          const f32x4 kv = *(const f32x4*)(kp + k);
          acc = fmaf(qv[0], kv[0], acc);
          acc = fmaf(qv[1], kv[1], acc);
          acc = fmaf(qv[2], kv[2], acc);
          acc = fmaf(qv[3], kv[3], acc);
        }
        scR[s] = acc * 0.125f; jR[s] = j;
      }
    }
  }

  float wsv[8]; int wjv[8];
#pragma unroll
  for (int e = 0; e < 8; e++) {
    float ms = scR[0]; int mj = jR[0];
#pragma unroll
    for (int s = 1; s < NS; s++)
      if (scR[s] > ms || (scR[s] == ms && jR[s] < mj)) { ms = scR[s]; mj = jR[s]; }
#pragma unroll
    for (int d = 1; d < 64; d <<= 1) {
      const float rs = __shfl_xor(ms, d);
      const int rj = __shfl_xor(mj, d);
      if (rs > ms || (rs == ms && rj < mj)) { ms = rs; mj = rj; }
    }
    wsv[e] = ms; wjv[e] = mj;
#pragma unroll
    for (int s = 0; s < NS; s++)
      if (jR[s] == mj) { scR[s] = -1e30f; jR[s] = 0x7fffffff; }
  }

  const float m0 = wsv[0];
  float ex[8], sum = 0.f;
#pragma unroll
  for (int r = 0; r < 8; r++) { ex[r] = expf(wsv[r] - m0); sum += ex[r]; }
  const float inv = 1.f / sum;

  if (lane == 0) {
#pragma unroll
    for (int r = 0; r < 8; r++) {
      out_idx[(size_t)tok * 8 + r] = (float)wjv[r];
      out_w[(size_t)tok * 8 + r] = ex[r] * inv;
    }
  }

  f32x4 a0 = {0.f,0.f,0.f,0.f}, a1 = a0, a2 = a0, a3 = a0;
#pragma unroll
  for (int r = 0; r < 8; r++) {
    const float w = ex[r] * inv;
    const float* vp = V + (size_t)(wjv[r] & (NKNOW - 1)) * 1024 + lane * 16;
    const f32x4 v0 = *(const f32x4*)(vp);
    const f32x4 v1 = *(const f32x4*)(vp + 4);
    const f32x4 v2 = *(const f32x4*)(vp + 8);
    const f32x4 v3 = *(const f32x4*)(vp + 12);
    a0 += w * v0; a1 += w * v1; a2 += w * v2; a3 += w * v3;
  }
  float* op = out + (size_t)tok * 1024 + lane * 16;
  *(f32x4*)(op)      = a0;
  *(f32x4*)(op + 4)  = a1;
  *(f32x4*)(op + 8)  = a2;
  *(f32x4*)(op + 12) = a3;
}

// ---------------------------------------------------------------------------
extern "C" void kernel_launch(void* const* d_in, const int* in_sizes, int n_in,
                              void* d_out, int out_size, void* d_ws, size_t ws_size,
                              hipStream_t stream) {
  const float* x  = (const float*)d_in[0];   // [2,4096,1024]
  const float* mw = (const float*)d_in[1];   // [2,4096,16]
  const float* cn = (const float*)d_in[2];   // [16,1024,64]
  const float* kK = (const float*)d_in[3];   // [16384,64]
  const float* kV = (const float*)d_in[4];   // [16384,1024]

  float* out  = (float*)d_out;               // 8192*1024
  float* oidx = out + (size_t)NTOK * D_MODEL;       // 8192*8
  float* ow   = oidx + (size_t)NTOK * TOPK;         // 8192*8

  // Workspace (43 MB, well under the 72.35 MB proven in R5):
  //  [0,32M)      T (k1m3 out, k1b in); GM overlays after k1b.
  //  [32M,34M)    Qf   [34M,35M) Qb   [35M,37M) Kb
  //  [37M,39M)    Bh   [39M,41M) Bm   [41M,43M) Bl
  float* T   = (float*)d_ws;
  us* GM     = (us*)d_ws;
  float* Qf  = (float*)((char*)d_ws + 33554432);
  us* Qb     = (us*)((char*)d_ws + 35651584);
  us* Kb     = (us*)((char*)d_ws + 36700160);
  us* Bh     = (us*)((char*)d_ws + 38797312);
  us* Bm     = (us*)((char*)d_ws + 40894464);
  us* Bl     = (us*)((char*)d_ws + 42991616);

  k1cb3<<<256, 256, 0, stream>>>(cn, Bh, Bm, Bl);
  k1m3<<<512, 256, 0, stream>>>(x, Bh, Bm, Bl, T);
  k1b_weight<<<2048, 256, 0, stream>>>(T, mw, Qf, Qb);
  k1c_cvt<<<1024, 256, 0, stream>>>(kK, Kb);
  k2s_screen<<<2048, 256, 0, stream>>>(Qb, Kb, GM);
  k2b_select<<<2048, 256, 0, stream>>>(Qf, kK, kV, GM, out, oidx, ow);

  (void)in_sizes; (void)n_in; (void)out_size; (void)ws_size;
}

// Round 13
// 293.753 us; speedup vs baseline: 10.2250x; 1.1564x over previous
//
#include <hip/hip_runtime.h>
#include <hip/hip_bf16.h>

#define D_MODEL 1024
#define RANK 64
#define NCOMP 16
#define NKNOW 16384
#define TOPK 8
#define NTOK 8192   // B*S
#define MAXG 48     // candidate-group cap per token (groups of 8 j's)
#define NS 6        // rescore slots per lane (MAXG*8/64)

typedef __attribute__((ext_vector_type(4))) float f32x4;
typedef __attribute__((ext_vector_type(8))) short s16x8;
typedef unsigned short us;

static __device__ __forceinline__ us f2bf(float f) {
  union { float f; unsigned u; } v; v.f = f;
  unsigned r = v.u + 0x7FFFu + ((v.u >> 16) & 1u);
  return (us)(r >> 16);
}
static __device__ __forceinline__ float bf2f(us h) {
  union { unsigned u; float f; } v; v.u = ((unsigned)h) << 16;
  return v.f;
}

// async global->LDS, 16B per lane; LDS dest = wave-uniform base + lane*16.
#define GLOAD16(g, l)                                                        \
  __builtin_amdgcn_global_load_lds(                                          \
      (const __attribute__((address_space(1))) void*)(g),                    \
      (__attribute__((address_space(3))) void*)(l), 16, 0, 0)

// RNE 3-way split: x = h + m + l + r, |r| <= 2^-24 |x|.
#define SPLIT3(f, h, m, l)                                                   \
  do {                                                                       \
    h = f2bf(f);                                                             \
    const float r1_ = (f) - bf2f(h);                                         \
    m = f2bf(r1_);                                                           \
    const float r2_ = r1_ - bf2f(m);                                         \
    l = f2bf(r2_);                                                           \
  } while (0)

// ---------------------------------------------------------------------------
// K1cb3: transpose + 3-way RNE-split CN -> Bh,Bm,Bl [1024 c][1024 d],
// Bt[c][d] = cn[c>>6][d][c&63]. Structure proven in R6 (k1cb).
// ---------------------------------------------------------------------------
__global__ __launch_bounds__(256) void k1cb3(const float* __restrict__ CN,
                                             us* __restrict__ Bh,
                                             us* __restrict__ Bm,
                                             us* __restrict__ Bl) {
  __shared__ float tile[64][65];
  const int n = blockIdx.x >> 4, dt = blockIdx.x & 15;
  const int tid = threadIdx.x;
  {
    const int d = tid >> 2, rc = (tid & 3) * 16;
    const float* p = CN + ((size_t)n * 1024 + dt * 64 + d) * 64 + rc;
#pragma unroll
    for (int e = 0; e < 16; e += 4) {
      const f32x4 v = *(const f32x4*)(p + e);
      tile[d][rc + e]     = v[0];
      tile[d][rc + e + 1] = v[1];
      tile[d][rc + e + 2] = v[2];
      tile[d][rc + e + 3] = v[3];
    }
  }
  __syncthreads();
  {
    const int r = tid >> 2, dc = (tid & 3) * 16;
    s16x8 oh[2], om[2], ol[2];
#pragma unroll
    for (int g = 0; g < 2; g++)
#pragma unroll
      for (int e = 0; e < 8; e++) {
        const float v = tile[dc + g * 8 + e][r];
        us h, m, l;
        SPLIT3(v, h, m, l);
        oh[g][e] = (short)h; om[g][e] = (short)m; ol[g][e] = (short)l;
      }
    const size_t base = (size_t)(n * 64 + r) * 1024 + dt * 64 + dc;
#pragma unroll
    for (int g = 0; g < 2; g++) {
      *(s16x8*)(Bh + base + g * 8) = oh[g];
      *(s16x8*)(Bm + base + g * 8) = om[g];
      *(s16x8*)(Bl + base + g * 8) = ol[g];
    }
  }
}

// ---------------------------------------------------------------------------
// K1m3: T = Xh@Bh + [corrections] with SPLIT ACCUMULATORS (R12-proven,
// byte-identical). 128x128 tile, 4 waves, BK=32, grid 512.
// ---------------------------------------------------------------------------
__global__ __launch_bounds__(256) void k1m3(const float* __restrict__ X,
                                            const us* __restrict__ Bh,
                                            const us* __restrict__ Bm,
                                            const us* __restrict__ Bl,
                                            float* __restrict__ T) {
  __shared__ us As[3][4][128][8];      // 24 KB [split][kq][row][8]
  __shared__ us Bs[2][3][4][128][8];   // 48 KB [buf][split][kq][col][8]
  const int tid = threadIdx.x;
  const int w = tid >> 6, lane = tid & 63;
  const int wr = w >> 1, wc = w & 1;
  const int l15 = lane & 15, kq = lane >> 4;
  const int by = blockIdx.x >> 3, bx = blockIdx.x & 7;
  const int row0 = by * 128, col0 = bx * 128;

  const int sr = tid & 127, sh = tid >> 7;
  const float* xp = X + (size_t)(row0 + sr) * 1024 + sh * 16;

  const us* bsrc0[3]; const us* bsrc1[3];
  int bs_s[3], bs_q[3];
#pragma unroll
  for (int i = 0; i < 3; i++) {
    const int p = w * 3 + i;
    const int s = p >> 2, q = p & 3;
    bs_s[i] = s; bs_q[i] = q;
    const us* base = (s == 0) ? Bh : (s == 1) ? Bm : Bl;
    bsrc0[i] = base + (size_t)(col0 + lane) * 1024 + q * 8;
    bsrc1[i] = base + (size_t)(col0 + 64 + lane) * 1024 + q * 8;
  }

  f32x4 accH[4][4] = {};   // hh product only
  f32x4 accC[4][4] = {};   // correction products
  f32x4 xr[4];
  s16x8 creg[6];

#pragma unroll
  for (int i = 0; i < 3; i++) {
    GLOAD16(bsrc0[i], &Bs[0][bs_s[i]][bs_q[i]][0][0]);
    GLOAD16(bsrc1[i], &Bs[0][bs_s[i]][bs_q[i]][64][0]);
  }
#pragma unroll
  for (int g = 0; g < 4; g++) xr[g] = *(const f32x4*)(xp + g * 4);
#pragma unroll
  for (int g = 0; g < 4; g++)
#pragma unroll
    for (int e = 0; e < 4; e++) {
      us h, m, l;
      SPLIT3(xr[g][e], h, m, l);
      const int c = (g * 4 + e) >> 3, e8 = (g * 4 + e) & 7;
      creg[c][e8] = (short)h; creg[2 + c][e8] = (short)m; creg[4 + c][e8] = (short)l;
    }

  for (int kk = 0; kk < 32; ++kk) {
    const int cur = kk & 1;
    *(s16x8*)&As[0][sh * 2][sr][0]     = creg[0];
    *(s16x8*)&As[0][sh * 2 + 1][sr][0] = creg[1];
    *(s16x8*)&As[1][sh * 2][sr][0]     = creg[2];
    *(s16x8*)&As[1][sh * 2 + 1][sr][0] = creg[3];
    *(s16x8*)&As[2][sh * 2][sr][0]     = creg[4];
    *(s16x8*)&As[2][sh * 2 + 1][sr][0] = creg[5];
    __syncthreads();   // drains B gloads for kk (vmcnt 0) + As writes

    if (kk + 1 < 32) {
      const int ko = (kk + 1) * 32;
#pragma unroll
      for (int i = 0; i < 3; i++) {
        GLOAD16(bsrc0[i] + ko, &Bs[cur ^ 1][bs_s[i]][bs_q[i]][0][0]);
        GLOAD16(bsrc1[i] + ko, &Bs[cur ^ 1][bs_s[i]][bs_q[i]][64][0]);
      }
#pragma unroll
      for (int g = 0; g < 4; g++) xr[g] = *(const f32x4*)(xp + ko + g * 4);
    }

#define PROD(sa, sb, ACC)                                                     \
    do {                                                                      \
      s16x8 af[4];                                                            \
      _Pragma("unroll")                                                       \
      for (int mm = 0; mm < 4; mm++)                                          \
        af[mm] = *(const s16x8*)&As[sa][kq][wr * 64 + mm * 16 + l15][0];      \
      _Pragma("unroll")                                                       \
      for (int nn = 0; nn < 4; nn++) {                                        \
        const s16x8 bfr =                                                     \
            *(const s16x8*)&Bs[cur][sb][kq][wc * 64 + nn * 16 + l15][0];      \
        _Pragma("unroll")                                                     \
        for (int mm = 0; mm < 4; mm++)                                        \
          ACC[mm][nn] = __builtin_amdgcn_mfma_f32_16x16x32_bf16(              \
              af[mm], bfr, ACC[mm][nn], 0, 0, 0);                             \
      }                                                                       \
    } while (0)

    PROD(0, 0, accH);
    PROD(0, 1, accC); PROD(1, 0, accC); PROD(0, 2, accC);
    PROD(2, 0, accC); PROD(1, 1, accC);
#undef PROD

    if (kk + 1 < 32) {
#pragma unroll
      for (int g = 0; g < 4; g++)
#pragma unroll
        for (int e = 0; e < 4; e++) {
          us h, m, l;
          SPLIT3(xr[g][e], h, m, l);
          const int c = (g * 4 + e) >> 3, e8 = (g * 4 + e) & 7;
          creg[c][e8] = (short)h; creg[2 + c][e8] = (short)m;
          creg[4 + c][e8] = (short)l;
        }
    }
    __syncthreads();   // all waves done reading As/Bs[cur]
  }

#pragma unroll
  for (int mm = 0; mm < 4; mm++)
#pragma unroll
    for (int nn = 0; nn < 4; nn++)
#pragma unroll
      for (int r = 0; r < 4; r++)
        T[(size_t)(row0 + wr * 64 + mm * 16 + kq * 4 + r) * 1024
          + col0 + wc * 64 + nn * 16 + l15] = accH[mm][nn][r] + accC[mm][nn][r];
}

// ---------------------------------------------------------------------------
// K1b: Q[tok][r] = sum_n mw[tok][n] * T[tok][n*64+r]; also emit bf16 copy.
// ---------------------------------------------------------------------------
__global__ __launch_bounds__(256) void k1b_weight(const float* __restrict__ T,
                                                  const float* __restrict__ MW,
                                                  float* __restrict__ Qf,
                                                  us* __restrict__ Qb) {
  const int gid = blockIdx.x * 256 + threadIdx.x;  // 0..524287
  const int tok = gid >> 6, r = gid & 63;
  float q = 0.f;
#pragma unroll
  for (int n = 0; n < 16; n++)
    q = fmaf(MW[tok * 16 + n], T[(size_t)tok * 1024 + n * 64 + r], q);
  Qf[gid] = q;
  Qb[gid] = f2bf(q);
}

// ---------------------------------------------------------------------------
// K1c: Kb = bf16(knowledge_K)
// ---------------------------------------------------------------------------
__global__ __launch_bounds__(256) void k1c_cvt(const float* __restrict__ Kf,
                                               us* __restrict__ Kb) {
  const int gid = blockIdx.x * 256 + threadIdx.x;  // one per 4 elems
  f32x4 v = *(const f32x4*)(Kf + (size_t)gid * 4);
  us o0 = f2bf(v[0]), o1 = f2bf(v[1]), o2 = f2bf(v[2]), o3 = f2bf(v[3]);
  unsigned long long pack = (unsigned long long)o0 | ((unsigned long long)o1 << 16)
                          | ((unsigned long long)o2 << 32) | ((unsigned long long)o3 << 48);
  *(unsigned long long*)(Kb + (size_t)gid * 4) = pack;
}

// ---------------------------------------------------------------------------
// K2s v2: screening with TWO token-groups per wave. Each af (Kb fragment) is
// loaded once and feeds 2 B-fragments (4 MFMAs, 2 independent acc chains) ->
// Kb L2 traffic halves (1 GB -> 0.5 GB) and wave count halves (8192 -> 4096).
// GM values are bit-identical to v1 (same MFMA, same reduce, same layout).
// grid 1024; wave gw=(blk*4+wv): tg=gw>>4 (32 tokens, tb=tg*32), jsl=gw&15.
// ---------------------------------------------------------------------------
__global__ __launch_bounds__(256) void k2s_screen(
    const us* __restrict__ Qb, const us* __restrict__ Kb,
    us* __restrict__ GM) {
  __shared__ us sh[4][32][136];   // 34.8 KB
  const int tid = threadIdx.x;
  const int wv = tid >> 6, lane = tid & 63;
  const int gw = blockIdx.x * 4 + wv;     // 0..4095
  const int tg = gw >> 4;                 // token group 0..255 (32 tokens)
  const int jsl = gw & 15;                // j-slice 0..15
  const int tb = tg * 32;
  const int myTok = lane & 15;
  const int slice = lane >> 4;            // 0..3

  // B-fragments for both 16-token halves
  const s16x8 bfa0 = *(const s16x8*)(Qb + (size_t)(tb + myTok) * 64 + slice * 8);
  const s16x8 bfa1 = *(const s16x8*)(Qb + (size_t)(tb + myTok) * 64 + 32 + slice * 8);
  const s16x8 bfb0 = *(const s16x8*)(Qb + (size_t)(tb + 16 + myTok) * 64 + slice * 8);
  const s16x8 bfb1 = *(const s16x8*)(Qb + (size_t)(tb + 16 + myTok) * 64 + 32 + slice * 8);

  const int j0 = jsl * 1024;
  const us* ap0 = Kb + (size_t)(j0 + myTok) * 64 + slice * 8;
  s16x8 af0 = *(const s16x8*)(ap0);
  s16x8 af1 = *(const s16x8*)(ap0 + 32);
  const bool writer = (slice & 1) == 0;
  const int sub = slice >> 1;

  for (int tt = 0; tt < 64; ++tt) {
    f32x4 ca = {0.f, 0.f, 0.f, 0.f};
    f32x4 cb = {0.f, 0.f, 0.f, 0.f};
    ca = __builtin_amdgcn_mfma_f32_16x16x32_bf16(af0, bfa0, ca, 0, 0, 0);
    cb = __builtin_amdgcn_mfma_f32_16x16x32_bf16(af0, bfb0, cb, 0, 0, 0);
    ca = __builtin_amdgcn_mfma_f32_16x16x32_bf16(af1, bfa1, ca, 0, 0, 0);
    cb = __builtin_amdgcn_mfma_f32_16x16x32_bf16(af1, bfb1, cb, 0, 0, 0);
    if (tt + 1 < 64) {
      const us* ap = ap0 + (size_t)(tt + 1) * 16 * 64;
      af0 = *(const s16x8*)(ap);
      af1 = *(const s16x8*)(ap + 32);
    }
    const float gma4 = fmaxf(fmaxf(ca[0], ca[1]), fmaxf(ca[2], ca[3]));
    const float gma8 = fmaxf(gma4, __shfl_xor(gma4, 16));
    const float gmb4 = fmaxf(fmaxf(cb[0], cb[1]), fmaxf(cb[2], cb[3]));
    const float gmb8 = fmaxf(gmb4, __shfl_xor(gmb4, 16));
    if (writer) {
      sh[wv][myTok][2 * tt + sub] = f2bf(gma8);
      sh[wv][16 + myTok][2 * tt + sub] = f2bf(gmb8);
    }
  }
  __syncthreads();
  // coalesced write: lane -> (token = lane>>1, half = lane&1), 8 x 16B chunks
  {
    const int t = lane >> 1;
    const int half = (lane & 1) * 64;
    us* orow = GM + (size_t)(tb + t) * 2048 + jsl * 128 + half;
#pragma unroll
    for (int ch = 0; ch < 8; ch++)
      *(s16x8*)(orow + ch * 8) = *(const s16x8*)&sh[wv][t][half + ch * 8];
  }
}

// ---------------------------------------------------------------------------
// K2b: one wave per token. 2048 group-maxima -> thr = 8th-largest lane-max -
// margin -> compact groups -> exact f32 rescore -> exact top-8 (desc score,
// asc idx) -> softmax -> gather V -> outputs. V-gather index masked to
// [0,NKNOW) so a sentinel can never fault (no effect on correct runs).
// ---------------------------------------------------------------------------
__global__ __launch_bounds__(256) void k2b_select(
    const float* __restrict__ Qf, const float* __restrict__ Kf,
    const float* __restrict__ V, const us* __restrict__ GM,
    float* __restrict__ out, float* __restrict__ out_idx,
    float* __restrict__ out_w) {
  __shared__ float qsh[4][64];
  __shared__ int csh[4][MAXG];
  __shared__ int scnt[4];
  const int tid = threadIdx.x;
  const int wv = tid >> 6, lane = tid & 63;
  const int tok = blockIdx.x * 4 + wv;    // 0..8191

  if (lane == 0) scnt[wv] = 0;
  qsh[wv][lane] = Qf[(size_t)tok * 64 + lane];

  unsigned long long gv[8];
  const unsigned long long* gmp =
      (const unsigned long long*)(GM + (size_t)tok * 2048);
#pragma unroll
  for (int i = 0; i < 8; i++) gv[i] = gmp[i * 64 + lane];

  float lm = -1e30f;
#pragma unroll
  for (int i = 0; i < 8; i++)
#pragma unroll
    for (int e = 0; e < 4; e++)
      lm = fmaxf(lm, bf2f((us)(gv[i] >> (e * 16))));

  float v = lm, m8 = -1e30f;
#pragma unroll
  for (int e = 0; e < 8; e++) {
    float m = v;
#pragma unroll
    for (int d = 1; d < 64; d <<= 1) m = fmaxf(m, __shfl_xor(m, d));
    m8 = m;
    if (e < 7) v = (v == m) ? -1e30f : v;
  }
  const float thr = m8 - 0.04f;

#pragma unroll
  for (int i = 0; i < 8; i++) {
#pragma unroll
    for (int e = 0; e < 4; e++) {
      const float g = bf2f((us)(gv[i] >> (e * 16)));
      if (g >= thr) {
        const int s = atomicAdd(&scnt[wv], 1);
        if (s < MAXG) csh[wv][s] = i * 256 + lane * 4 + e;
      }
    }
  }
  int ng = scnt[wv];
  if (ng > MAXG) ng = MAXG;
  const int nj = ng * 8;

  float scR[NS]; int jR[NS];
#pragma unroll
  for (int s = 0; s < NS; s++) {
    scR[s] = -1e30f; jR[s] = 0x7fffffff;
    if (s * 64 < nj) {
      const int ci = s * 64 + lane;
      if (ci < nj) {
        const int j = csh[wv][ci >> 3] * 8 + (ci & 7);
        const float* kp = Kf + (size_t)j * 64;
        float acc = 0.f;
#pragma unroll
        for (int k = 0; k < 64; k += 4) {
          const f32x4 qv = *(const f32x4*)&qsh[wv][k];
          const f32x4 kv = *(const f32x4*)(kp + k);
          acc = fmaf(qv[0], kv[0], acc);
          acc = fmaf(qv[1], kv[1], acc);
          acc = fmaf(qv[2], kv[2], acc);
          acc = fmaf(qv[3], kv[3], acc);
        }
        scR[s] = acc * 0.125f; jR[s] = j;
      }
    }
  }

  float wsv[8]; int wjv[8];
#pragma unroll
  for (int e = 0; e < 8; e++) {
    float ms = scR[0]; int mj = jR[0];
#pragma unroll
    for (int s = 1; s < NS; s++)
      if (scR[s] > ms || (scR[s] == ms && jR[s] < mj)) { ms = scR[s]; mj = jR[s]; }
#pragma unroll
    for (int d = 1; d < 64; d <<= 1) {
      const float rs = __shfl_xor(ms, d);
      const int rj = __shfl_xor(mj, d);
      if (rs > ms || (rs == ms && rj < mj)) { ms = rs; mj = rj; }
    }
    wsv[e] = ms; wjv[e] = mj;
#pragma unroll
    for (int s = 0; s < NS; s++)
      if (jR[s] == mj) { scR[s] = -1e30f; jR[s] = 0x7fffffff; }
  }

  const float m0 = wsv[0];
  float ex[8], sum = 0.f;
#pragma unroll
  for (int r = 0; r < 8; r++) { ex[r] = expf(wsv[r] - m0); sum += ex[r]; }
  const float inv = 1.f / sum;

  if (lane == 0) {
#pragma unroll
    for (int r = 0; r < 8; r++) {
      out_idx[(size_t)tok * 8 + r] = (float)wjv[r];
      out_w[(size_t)tok * 8 + r] = ex[r] * inv;
    }
  }

  f32x4 a0 = {0.f,0.f,0.f,0.f}, a1 = a0, a2 = a0, a3 = a0;
#pragma unroll
  for (int r = 0; r < 8; r++) {
    const float w = ex[r] * inv;
    const float* vp = V + (size_t)(wjv[r] & (NKNOW - 1)) * 1024 + lane * 16;
    const f32x4 v0 = *(const f32x4*)(vp);
    const f32x4 v1 = *(const f32x4*)(vp + 4);
    const f32x4 v2 = *(const f32x4*)(vp + 8);
    const f32x4 v3 = *(const f32x4*)(vp + 12);
    a0 += w * v0; a1 += w * v1; a2 += w * v2; a3 += w * v3;
  }
  float* op = out + (size_t)tok * 1024 + lane * 16;
  *(f32x4*)(op)      = a0;
  *(f32x4*)(op + 4)  = a1;
  *(f32x4*)(op + 8)  = a2;
  *(f32x4*)(op + 12) = a3;
}

// ---------------------------------------------------------------------------
extern "C" void kernel_launch(void* const* d_in, const int* in_sizes, int n_in,
                              void* d_out, int out_size, void* d_ws, size_t ws_size,
                              hipStream_t stream) {
  const float* x  = (const float*)d_in[0];   // [2,4096,1024]
  const float* mw = (const float*)d_in[1];   // [2,4096,16]
  const float* cn = (const float*)d_in[2];   // [16,1024,64]
  const float* kK = (const float*)d_in[3];   // [16384,64]
  const float* kV = (const float*)d_in[4];   // [16384,1024]

  float* out  = (float*)d_out;               // 8192*1024
  float* oidx = out + (size_t)NTOK * D_MODEL;       // 8192*8
  float* ow   = oidx + (size_t)NTOK * TOPK;         // 8192*8

  // Workspace (43 MB, well under the 72.35 MB proven in R5):
  //  [0,32M)      T (k1m3 out, k1b in); GM overlays after k1b.
  //  [32M,34M)    Qf   [34M,35M) Qb   [35M,37M) Kb
  //  [37M,39M)    Bh   [39M,41M) Bm   [41M,43M) Bl
  float* T   = (float*)d_ws;
  us* GM     = (us*)d_ws;
  float* Qf  = (float*)((char*)d_ws + 33554432);
  us* Qb     = (us*)((char*)d_ws + 35651584);
  us* Kb     = (us*)((char*)d_ws + 36700160);
  us* Bh     = (us*)((char*)d_ws + 38797312);
  us* Bm     = (us*)((char*)d_ws + 40894464);
  us* Bl     = (us*)((char*)d_ws + 42991616);

  k1cb3<<<256, 256, 0, stream>>>(cn, Bh, Bm, Bl);
  k1m3<<<512, 256, 0, stream>>>(x, Bh, Bm, Bl, T);
  k1b_weight<<<2048, 256, 0, stream>>>(T, mw, Qf, Qb);
  k1c_cvt<<<1024, 256, 0, stream>>>(kK, Kb);
  k2s_screen<<<1024, 256, 0, stream>>>(Qb, Kb, GM);
  k2b_select<<<2048, 256, 0, stream>>>(Qf, kK, kV, GM, out, oidx, ow);

  (void)in_sizes; (void)n_in; (void)out_size; (void)ws_size;
}